// Round 6
// baseline (193.806 us; speedup 1.0000x reference)
//
#include <hip/hip_runtime.h>

typedef __attribute__((ext_vector_type(8))) _Float16 f16x8;
typedef __attribute__((ext_vector_type(16))) float f32x16;

#define MFMA32(a, b, c) __builtin_amdgcn_mfma_f32_32x32x16_f16((a), (b), (c), 0, 0, 0)

// ---------------- helpers ----------------
__device__ __forceinline__ float tanh_fast(float x) {
  return 1.0f - 2.0f / (__expf(2.0f * x) + 1.0f);
}

// ---------------- K1: quantum sim + q-moments; tail blocks convert weights ----------------
// Weight layouts for coalesced MFMA B-fragments: w?t[kblock][col][8 halves],
// so lane m32 (col = base+m32) reads 16B at addr ((kblock*256+col)*8)*2 —
// 32 lanes = 512B contiguous.
__global__ __launch_bounds__(256) void k_quantum(
    const float4* __restrict__ x, const float* __restrict__ qp,
    float4* __restrict__ qout, float* __restrict__ stats, int QB,
    const float* __restrict__ w2, const float* __restrict__ w3,
    _Float16* __restrict__ w2t, _Float16* __restrict__ w3t)
{
  int tid = threadIdx.x;

  if (blockIdx.x >= QB) {   // weight-conversion tail blocks (256 of them)
    int i = (blockIdx.x - QB) * 256 + tid;   // 0..65535
    {
      int col = i >> 8, k = i & 255;
      w3t[((k >> 3) * 256 + col) * 8 + (k & 7)] = (_Float16)w3[i];
    }
    if (i < 32768) {
      int col = i >> 7, k = i & 127;
      w2t[((k >> 3) * 256 + col) * 8 + (k & 7)] = (_Float16)w2[i];
    }
    return;
  }

  size_t r = (size_t)blockIdx.x * 256 + tid;
  float4 xr = x[r];
  float xv[4] = {xr.x, xr.y, xr.z, xr.w};

  float re[16], im[16];
#pragma unroll
  for (int i = 0; i < 16; i++) { re[i] = 0.f; im[i] = 0.f; }
  re[0] = 1.f;

#pragma unroll
  for (int d = 0; d < 3; d++) {
#pragma unroll
    for (int q = 0; q < 4; q++) {
      float th = 0.5f * (xv[q] + qp[d * 8 + q]);
      float s, c; __sincosf(th, &s, &c);
      int m = 8 >> q;
#pragma unroll
      for (int i = 0; i < 16; i++) if (!(i & m)) {
        int i1 = i | m;
        float r0 = re[i], i0 = im[i], r1 = re[i1], i1v = im[i1];
        re[i]  = c * r0 - s * r1;  im[i]  = c * i0 - s * i1v;
        re[i1] = s * r0 + c * r1;  im[i1] = s * i0 + c * i1v;
      }
    }
#pragma unroll
    for (int q = 0; q < 4; q++) {
      int mc = 8 >> q, mt = 8 >> ((q + 1) & 3);
#pragma unroll
      for (int i = 0; i < 16; i++) if ((i & mc) && !(i & mt)) {
        int i1 = i | mt;
        float tr = re[i]; re[i] = re[i1]; re[i1] = tr;
        float ti = im[i]; im[i] = im[i1]; im[i1] = ti;
      }
    }
#pragma unroll
    for (int q = 0; q < 4; q++) {
      float th = 0.5f * qp[d * 8 + 4 + q];
      float s, c; __sincosf(th, &s, &c);
      int m = 8 >> q;
#pragma unroll
      for (int i = 0; i < 16; i++) {
        float pi = (i & m) ? s : -s;
        float r0 = re[i], i0 = im[i];
        re[i] = r0 * c - i0 * pi;
        im[i] = r0 * pi + i0 * c;
      }
    }
  }

  float p[16];
#pragma unroll
  for (int i = 0; i < 16; i++) p[i] = re[i] * re[i] + im[i] * im[i];
  float z[4];
#pragma unroll
  for (int q = 0; q < 4; q++) {
    int m = 8 >> q; float acc = 0.f;
#pragma unroll
    for (int i = 0; i < 16; i++) acc += (i & m) ? -p[i] : p[i];
    z[q] = acc;
  }
  qout[r] = make_float4(z[0], z[1], z[2], z[3]);

  float st[14];
  st[0] = z[0]; st[1] = z[1]; st[2] = z[2]; st[3] = z[3];
  int p5 = 4;
#pragma unroll
  for (int a = 0; a < 4; a++)
#pragma unroll
    for (int b = a; b < 4; b++) st[p5++] = z[a] * z[b];

  __shared__ float part[4][14];
  int lane = tid & 63, wv = tid >> 6;
#pragma unroll
  for (int s = 0; s < 14; s++) {
    float v = st[s];
#pragma unroll
    for (int o = 32; o; o >>= 1) v += __shfl_down(v, o, 64);
    if (lane == 0) part[wv][s] = v;
  }
  __syncthreads();
  if (tid < 14)
    atomicAdd(stats + tid, part[0][tid] + part[1][tid] + part[2][tid] + part[3][tid]);
}

// ---------------- K2: fold BN1 into effective fc1 weights ----------------
__global__ void k_prep1(const float* __restrict__ w1, const float* __restrict__ b1,
                        const float* __restrict__ g, const float* __restrict__ bb,
                        const float* __restrict__ stats, float* __restrict__ w1e,
                        float* __restrict__ b1e, float invB)
{
  int j = threadIdx.x;   // 128
  float qb0 = stats[0] * invB, qb1 = stats[1] * invB, qb2 = stats[2] * invB, qb3 = stats[3] * invB;
  float M00 = stats[4] * invB, M01 = stats[5] * invB, M02 = stats[6] * invB, M03 = stats[7] * invB;
  float M11 = stats[8] * invB, M12 = stats[9] * invB, M13 = stats[10] * invB;
  float M22 = stats[11] * invB, M23 = stats[12] * invB, M33 = stats[13] * invB;
  float w0 = w1[j * 4 + 0], wv1 = w1[j * 4 + 1], wv2 = w1[j * 4 + 2], wv3 = w1[j * 4 + 3];
  float b = b1[j];
  float wq = w0 * qb0 + wv1 * qb1 + wv2 * qb2 + wv3 * qb3;
  float m = wq + b;
  float quad = w0 * w0 * M00 + wv1 * wv1 * M11 + wv2 * wv2 * M22 + wv3 * wv3 * M33
             + 2.f * (w0 * wv1 * M01 + w0 * wv2 * M02 + w0 * wv3 * M03
                    + wv1 * wv2 * M12 + wv1 * wv3 * M13 + wv2 * wv3 * M23);
  float e2 = quad + 2.f * b * wq + b * b;
  float var = e2 - m * m;
  float s = g[j] * rsqrtf(var + 1e-5f);
  w1e[j * 4 + 0] = s * w0; w1e[j * 4 + 1] = s * wv1;
  w1e[j * 4 + 2] = s * wv2; w1e[j * 4 + 3] = s * wv3;
  b1e[j] = s * b + bb[j] - s * m;
}

// ---------------- K3: fc2 -> h2g (fp16, K-blocked) + BN2 batch stats ----------------
// 128 rows/block; wave w owns cols [w*64, w*64+64) as two 32-col groups.
// h2g layout per tile: [kblock(32)][row(128)][8 halves] -> A-frag loads in k_fc3
// are 512B-contiguous per 32 lanes.
__global__ __launch_bounds__(256, 2) void k_fc2h(
    const float4* __restrict__ q, const float4* __restrict__ w1e4,
    const float* __restrict__ b1e, const _Float16* __restrict__ w2t,
    const float* __restrict__ b2, _Float16* __restrict__ h2g,
    float* __restrict__ s2sum, float* __restrict__ s2sq)
{
  __shared__ __align__(16) float4 qs[128];                 // 2 KB
  __shared__ __align__(16) _Float16 un[128 * 260];         // 66.6 KB union
  _Float16* a1 = un;    // [128][132] during fc2 phase
  _Float16* h2 = un;    // [128][260] during transpose phase

  int t = threadIdx.x;
  int lane = t & 63, w = t >> 6, m32 = lane & 31, hh = lane >> 5;
  size_t rowBase = (size_t)blockIdx.x * 128;

  if (t < 128) qs[t] = q[rowBase + t];
  __syncthreads();

  // ---- stage a1 = relu(W1e q + b1e) as fp16, stride 132 (66 words %32=2 -> free) ----
  {
    int j = t & 127;
    float4 w1 = w1e4[j];
    float b1v = b1e[j];
    int rb = (t >> 7) * 64;
#pragma unroll 8
    for (int i = 0; i < 64; i++) {
      float4 qv = qs[rb + i];
      float v = fmaf(w1.x, qv.x, fmaf(w1.y, qv.y, fmaf(w1.z, qv.z, fmaf(w1.w, qv.w, b1v))));
      a1[(rb + i) * 132 + j] = (_Float16)fmaxf(v, 0.f);
    }
  }
  __syncthreads();

  // ---- fc2 K-loop (B-frags from w2t: coalesced 512B segments) ----
  f32x16 acc[4][2];
#pragma unroll
  for (int mt = 0; mt < 4; mt++)
#pragma unroll
    for (int nt = 0; nt < 2; nt++)
#pragma unroll
      for (int r = 0; r < 16; r++) acc[mt][nt][r] = 0.f;

#pragma unroll
  for (int ks = 0; ks < 8; ks++) {               // K = 128, step 16
    int kb = ks * 16 + hh * 8;
    int kblock = ks * 2 + hh;
    f16x8 bfr[2];
#pragma unroll
    for (int nt = 0; nt < 2; nt++)
      bfr[nt] = *(const f16x8*)(w2t + (size_t)(kblock * 256 + w * 64 + nt * 32 + m32) * 8);
#pragma unroll
    for (int mt = 0; mt < 4; mt++) {
      f16x8 afr = *(const f16x8*)&a1[(mt * 32 + m32) * 132 + kb];
#pragma unroll
      for (int nt = 0; nt < 2; nt++)
        acc[mt][nt] = MFMA32(afr, bfr[nt], acc[mt][nt]);
    }
  }

  // ---- per-column stats of h2 = acc + b2 over the block's 128 rows ----
#pragma unroll
  for (int nt = 0; nt < 2; nt++) {
    int col = w * 64 + nt * 32 + m32;
    float b2v = b2[col];
    float s = 0.f, ss = 0.f;
#pragma unroll
    for (int mt = 0; mt < 4; mt++)
#pragma unroll
      for (int r = 0; r < 16; r++) {
        float hv = acc[mt][nt][r] + b2v;
        s += hv; ss += hv * hv;
      }
    s += __shfl_down(s, 32, 64);
    ss += __shfl_down(ss, 32, 64);
    if (lane < 32) {
      atomicAdd(&s2sum[col], s);
      atomicAdd(&s2sq[col], ss);
    }
  }
  __syncthreads();   // a1 reads done; union becomes h2

  // ---- write raw h2 (b2 folded into BN2 offset) into LDS, stride 260 ----
#pragma unroll
  for (int nt = 0; nt < 2; nt++) {
    int col = w * 64 + nt * 32 + m32;
#pragma unroll
    for (int mt = 0; mt < 4; mt++)
#pragma unroll
      for (int r = 0; r < 16; r++) {
        int row = mt * 32 + (r & 3) + 8 * (r >> 2) + 4 * hh;
        h2[row * 260 + col] = (_Float16)acc[mt][nt][r];
      }
  }
  __syncthreads();

  // ---- LDS -> global h2g in K-blocked layout; 4 KB contiguous per instruction ----
  {
    size_t tileBase = (size_t)blockIdx.x * 4096;   // 32 kblocks * 128 rows
#pragma unroll
    for (int i = 0; i < 16; i++) {
      int idx8 = i * 256 + t;                      // = kblock*128 + row
      int kblock = idx8 >> 7, row = idx8 & 127;
      *(uint4*)(h2g + (tileBase + idx8) * 8) =
          *(const uint4*)(h2 + row * 260 + kblock * 8);
    }
  }
}

// ---------------- K4: BN2 affine coefficients (b2 folded in), fp16 ----------------
__global__ void k_prep2(const float* __restrict__ g, const float* __restrict__ bb,
                        const float* __restrict__ b2,
                        const float* __restrict__ s2sum, const float* __restrict__ s2sq,
                        _Float16* __restrict__ sc2h, _Float16* __restrict__ t2h, float invB)
{
  int j = threadIdx.x;   // 256
  float m = s2sum[j] * invB;
  float v = s2sq[j] * invB - m * m;
  float s = g[j] * rsqrtf(v + 1e-5f);
  sc2h[j] = (_Float16)s;
  t2h[j] = (_Float16)(bb[j] - m * s + b2[j] * s);   // a2 = relu(s*h_raw + t2)
}

// ---------------- K5: fc3 from K-blocked h2g — no LDS, all loads coalesced ----------------
// 128 rows/block; wave w owns cols [w*64, w*64+64)
__global__ __launch_bounds__(256) void k_fc3(
    const _Float16* __restrict__ h2g,
    const _Float16* __restrict__ sc2h, const _Float16* __restrict__ t2h,
    const _Float16* __restrict__ w3t, const float* __restrict__ b3,
    float* __restrict__ out)
{
  int t = threadIdx.x;
  int lane = t & 63, w = t >> 6, m32 = lane & 31, hh = lane >> 5;
  size_t rowBase = (size_t)blockIdx.x * 128;
  size_t tileBase = (size_t)blockIdx.x * 4096;

  f32x16 acc3[4][2];
#pragma unroll
  for (int mt = 0; mt < 4; mt++)
#pragma unroll
    for (int nt = 0; nt < 2; nt++)
#pragma unroll
      for (int r = 0; r < 16; r++) acc3[mt][nt][r] = 0.f;

#pragma unroll 4
  for (int ks = 0; ks < 16; ks++) {
    int kb = ks * 16 + hh * 8;
    int kblock = ks * 2 + hh;
    f16x8 sv8 = *(const f16x8*)(sc2h + kb);       // 2 addrs/wave -> broadcast
    f16x8 tv8 = *(const f16x8*)(t2h + kb);
    f16x8 bfr[2];
#pragma unroll
    for (int nt = 0; nt < 2; nt++)
      bfr[nt] = *(const f16x8*)(w3t + (size_t)(kblock * 256 + w * 64 + nt * 32 + m32) * 8);
#pragma unroll
    for (int mt = 0; mt < 4; mt++) {
      f16x8 hraw = *(const f16x8*)(h2g + (tileBase + kblock * 128 + mt * 32 + m32) * 8);
      f16x8 af = hraw * sv8 + tv8;                 // v_pk_fma_f16
#pragma unroll
      for (int j = 0; j < 8; j++)
        af[j] = (af[j] > (_Float16)0.f) ? af[j] : (_Float16)0.f;
#pragma unroll
      for (int nt = 0; nt < 2; nt++)
        acc3[mt][nt] = MFMA32(af, bfr[nt], acc3[mt][nt]);
    }
  }

  // ---- tanh epilogue: each store instr covers 2 full 128B lines ----
#pragma unroll
  for (int nt = 0; nt < 2; nt++) {
    int col = w * 64 + nt * 32 + m32;
    float b3v = b3[col];
#pragma unroll
    for (int mt = 0; mt < 4; mt++)
#pragma unroll
      for (int r = 0; r < 16; r++) {
        int row = mt * 32 + (r & 3) + 8 * (r >> 2) + 4 * hh;
        out[(rowBase + row) * 256 + col] = tanh_fast(acc3[mt][nt][r] + b3v);
      }
  }
}

// ---------------- host launcher ----------------
extern "C" void kernel_launch(void* const* d_in, const int* in_sizes, int n_in,
                              void* d_out, int out_size, void* d_ws, size_t ws_size,
                              hipStream_t stream) {
  const float* x     = (const float*)d_in[0];
  const float* qp    = (const float*)d_in[1];
  const float* fc1_w = (const float*)d_in[2];
  const float* fc1_b = (const float*)d_in[3];
  const float* bn1_g = (const float*)d_in[4];
  const float* bn1_b = (const float*)d_in[5];
  const float* fc2_w = (const float*)d_in[6];
  const float* fc2_b = (const float*)d_in[7];
  const float* bn2_g = (const float*)d_in[8];
  const float* bn2_b = (const float*)d_in[9];
  const float* fc3_w = (const float*)d_in[10];
  const float* fc3_b = (const float*)d_in[11];
  float* out = (float*)d_out;
  float* ws  = (float*)d_ws;

  int B = in_sizes[0] / 4;
  int QB = B / 256;

  // ws layout (floats): q[4B] | s1[16] | w1e[512] | b1e[128] | s2sum[256] | s2sq[256]
  //   | sc2h+t2h (256 fp16 each = 256 floats) | w2t[32768 fp16] | w3t[65536 fp16] | h2g[B*256 fp16]
  float* wq    = ws;
  float* s1    = ws + (size_t)4 * B;
  float* w1e   = s1 + 16;
  float* b1e   = w1e + 512;
  float* s2sum = b1e + 128;
  float* s2sq  = s2sum + 256;
  _Float16* sc2h = (_Float16*)(s2sq + 256);
  _Float16* t2h  = sc2h + 256;
  _Float16* w2t  = t2h + 256;
  _Float16* w3t  = w2t + 32768;
  _Float16* h2g  = w3t + 65536;

  hipMemsetAsync((void*)s1, 0, (16 + 512 + 128 + 256 + 256) * sizeof(float), stream);

  float invB = 1.0f / (float)B;

  k_quantum<<<QB + 256, 256, 0, stream>>>((const float4*)x, qp, (float4*)wq, s1, QB,
                                          fc2_w, fc3_w, w2t, w3t);
  k_prep1<<<1, 128, 0, stream>>>(fc1_w, fc1_b, bn1_g, bn1_b, s1, w1e, b1e, invB);
  k_fc2h<<<B / 128, 256, 0, stream>>>((const float4*)wq, (const float4*)w1e, b1e,
                                      w2t, fc2_b, h2g, s2sum, s2sq);
  k_prep2<<<1, 256, 0, stream>>>(bn2_g, bn2_b, fc2_b, s2sum, s2sq, sc2h, t2h, invB);
  k_fc3<<<B / 128, 256, 0, stream>>>(h2g, sc2h, t2h, w3t, fc3_b, out);
}

// Round 8
// 168.790 us; speedup vs baseline: 1.1482x; 1.1482x over previous
//
#include <hip/hip_runtime.h>

typedef __attribute__((ext_vector_type(8))) _Float16 f16x8;
typedef __attribute__((ext_vector_type(16))) float f32x16;

#define MFMA32(a, b, c) __builtin_amdgcn_mfma_f32_32x32x16_f16((a), (b), (c), 0, 0, 0)

__device__ __forceinline__ float tanh_fast(float x) {
  return 1.0f - 2.0f / (__expf(2.0f * x) + 1.0f);
}

// ---------------- K1: quantum sim + q-moments; tail blocks transpose weights ----------------
// w?t[kblock][col][8 halves]: B-frag load = 512B contiguous per 32 lanes.
__global__ __launch_bounds__(256) void k_quantum(
    const float4* __restrict__ x, const float* __restrict__ qp,
    float4* __restrict__ qout, float* __restrict__ stats, int QB,
    const float* __restrict__ w2, const float* __restrict__ w3,
    _Float16* __restrict__ w2t, _Float16* __restrict__ w3t)
{
  int tid = threadIdx.x;

  if (blockIdx.x >= QB) {   // 256 weight-transpose blocks
    int i = (blockIdx.x - QB) * 256 + tid;   // 0..65535
    {
      int col = i >> 8, k = i & 255;
      w3t[((k >> 3) * 256 + col) * 8 + (k & 7)] = (_Float16)w3[i];
    }
    if (i < 32768) {
      int col = i >> 7, k = i & 127;
      w2t[((k >> 3) * 256 + col) * 8 + (k & 7)] = (_Float16)w2[i];
    }
    return;
  }

  size_t r = (size_t)blockIdx.x * 256 + tid;
  float4 xr = x[r];
  float xv[4] = {xr.x, xr.y, xr.z, xr.w};

  float re[16], im[16];
#pragma unroll
  for (int i = 0; i < 16; i++) { re[i] = 0.f; im[i] = 0.f; }
  re[0] = 1.f;

#pragma unroll
  for (int d = 0; d < 3; d++) {
#pragma unroll
    for (int q = 0; q < 4; q++) {
      float th = 0.5f * (xv[q] + qp[d * 8 + q]);
      float s, c; __sincosf(th, &s, &c);
      int m = 8 >> q;
#pragma unroll
      for (int i = 0; i < 16; i++) if (!(i & m)) {
        int i1 = i | m;
        float r0 = re[i], i0 = im[i], r1 = re[i1], i1v = im[i1];
        re[i]  = c * r0 - s * r1;  im[i]  = c * i0 - s * i1v;
        re[i1] = s * r0 + c * r1;  im[i1] = s * i0 + c * i1v;
      }
    }
#pragma unroll
    for (int q = 0; q < 4; q++) {
      int mc = 8 >> q, mt = 8 >> ((q + 1) & 3);
#pragma unroll
      for (int i = 0; i < 16; i++) if ((i & mc) && !(i & mt)) {
        int i1 = i | mt;
        float tr = re[i]; re[i] = re[i1]; re[i1] = tr;
        float ti = im[i]; im[i] = im[i1]; im[i1] = ti;
      }
    }
#pragma unroll
    for (int q = 0; q < 4; q++) {
      float th = 0.5f * qp[d * 8 + 4 + q];
      float s, c; __sincosf(th, &s, &c);
      int m = 8 >> q;
#pragma unroll
      for (int i = 0; i < 16; i++) {
        float pi = (i & m) ? s : -s;
        float r0 = re[i], i0 = im[i];
        re[i] = r0 * c - i0 * pi;
        im[i] = r0 * pi + i0 * c;
      }
    }
  }

  float p[16];
#pragma unroll
  for (int i = 0; i < 16; i++) p[i] = re[i] * re[i] + im[i] * im[i];
  float z[4];
#pragma unroll
  for (int q = 0; q < 4; q++) {
    int m = 8 >> q; float acc = 0.f;
#pragma unroll
    for (int i = 0; i < 16; i++) acc += (i & m) ? -p[i] : p[i];
    z[q] = acc;
  }
  qout[r] = make_float4(z[0], z[1], z[2], z[3]);

  float st[14];
  st[0] = z[0]; st[1] = z[1]; st[2] = z[2]; st[3] = z[3];
  int p5 = 4;
#pragma unroll
  for (int a = 0; a < 4; a++)
#pragma unroll
    for (int b = a; b < 4; b++) st[p5++] = z[a] * z[b];

  __shared__ float part[4][14];
  int lane = tid & 63, wv = tid >> 6;
#pragma unroll
  for (int s = 0; s < 14; s++) {
    float v = st[s];
#pragma unroll
    for (int o = 32; o; o >>= 1) v += __shfl_down(v, o, 64);
    if (lane == 0) part[wv][s] = v;
  }
  __syncthreads();
  if (tid < 14)
    atomicAdd(stats + tid, part[0][tid] + part[1][tid] + part[2][tid] + part[3][tid]);
}

// ---------------- K2: fold BN1 into effective fc1 weights ----------------
__global__ void k_prep1(const float* __restrict__ w1, const float* __restrict__ b1,
                        const float* __restrict__ g, const float* __restrict__ bb,
                        const float* __restrict__ stats, float* __restrict__ w1e,
                        float* __restrict__ b1e, float invB)
{
  int j = threadIdx.x;   // 128
  float qb0 = stats[0] * invB, qb1 = stats[1] * invB, qb2 = stats[2] * invB, qb3 = stats[3] * invB;
  float M00 = stats[4] * invB, M01 = stats[5] * invB, M02 = stats[6] * invB, M03 = stats[7] * invB;
  float M11 = stats[8] * invB, M12 = stats[9] * invB, M13 = stats[10] * invB;
  float M22 = stats[11] * invB, M23 = stats[12] * invB, M33 = stats[13] * invB;
  float w0 = w1[j * 4 + 0], wv1 = w1[j * 4 + 1], wv2 = w1[j * 4 + 2], wv3 = w1[j * 4 + 3];
  float b = b1[j];
  float wq = w0 * qb0 + wv1 * qb1 + wv2 * qb2 + wv3 * qb3;
  float m = wq + b;
  float quad = w0 * w0 * M00 + wv1 * wv1 * M11 + wv2 * wv2 * M22 + wv3 * wv3 * M33
             + 2.f * (w0 * wv1 * M01 + w0 * wv2 * M02 + w0 * wv3 * M03
                    + wv1 * wv2 * M12 + wv1 * wv3 * M13 + wv2 * wv3 * M23);
  float e2 = quad + 2.f * b * wq + b * b;
  float var = e2 - m * m;
  float s = g[j] * rsqrtf(var + 1e-5f);
  w1e[j * 4 + 0] = s * w0; w1e[j * 4 + 1] = s * wv1;
  w1e[j * 4 + 2] = s * wv2; w1e[j * 4 + 3] = s * wv3;
  b1e[j] = s * b + bb[j] - s * m;
}

// ---------------- K3: fc2 -> BN2 batch stats (64 rows/block, 4 blocks/CU) ----------------
__global__ __launch_bounds__(256, 4) void k_fc2stats(
    const float4* __restrict__ q, const float4* __restrict__ w1e4,
    const float* __restrict__ b1e, const _Float16* __restrict__ w2t,
    const float* __restrict__ b2,
    float* __restrict__ s2sum, float* __restrict__ s2sq)
{
  __shared__ __align__(16) float4 qs[64];                  // 1 KB
  __shared__ __align__(16) _Float16 a1[64 * 132];          // 16.9 KB (2-way alias -> free)

  int t = threadIdx.x;
  int lane = t & 63, w = t >> 6, m32 = lane & 31, hh = lane >> 5;
  size_t rowBase = (size_t)blockIdx.x * 64;

  if (t < 64) qs[t] = q[rowBase + t];
  __syncthreads();

  // stage a1 = relu(W1e q + b1e), fp16
  {
    int j = t & 127;
    float4 w1 = w1e4[j];
    float b1v = b1e[j];
    int rb = (t >> 7) * 32;
#pragma unroll 8
    for (int i = 0; i < 32; i++) {
      float4 qv = qs[rb + i];
      float v = fmaf(w1.x, qv.x, fmaf(w1.y, qv.y, fmaf(w1.z, qv.z, fmaf(w1.w, qv.w, b1v))));
      a1[(rb + i) * 132 + j] = (_Float16)fmaxf(v, 0.f);
    }
  }
  __syncthreads();

  f32x16 acc[2][2];
#pragma unroll
  for (int mt = 0; mt < 2; mt++)
#pragma unroll
    for (int nt = 0; nt < 2; nt++)
#pragma unroll
      for (int r = 0; r < 16; r++) acc[mt][nt][r] = 0.f;

#pragma unroll
  for (int ks = 0; ks < 8; ks++) {               // K = 128
    int kb = ks * 16 + hh * 8;
    int kblock = ks * 2 + hh;
    f16x8 bfr[2];
#pragma unroll
    for (int nt = 0; nt < 2; nt++)
      bfr[nt] = *(const f16x8*)(w2t + (size_t)(kblock * 256 + w * 64 + nt * 32 + m32) * 8);
#pragma unroll
    for (int mt = 0; mt < 2; mt++) {
      f16x8 afr = *(const f16x8*)&a1[(mt * 32 + m32) * 132 + kb];
#pragma unroll
      for (int nt = 0; nt < 2; nt++)
        acc[mt][nt] = MFMA32(afr, bfr[nt], acc[mt][nt]);
    }
  }

  // per-column sum & sumsq of h2 = acc + b2 over the block's 64 rows
#pragma unroll
  for (int nt = 0; nt < 2; nt++) {
    int col = w * 64 + nt * 32 + m32;
    float b2v = b2[col];
    float s = 0.f, ss = 0.f;
#pragma unroll
    for (int mt = 0; mt < 2; mt++)
#pragma unroll
      for (int r = 0; r < 16; r++) {
        float hv = acc[mt][nt][r] + b2v;
        s += hv; ss += hv * hv;
      }
    s += __shfl_down(s, 32, 64);
    ss += __shfl_down(ss, 32, 64);
    if (lane < 32) {
      atomicAdd(&s2sum[col], s);
      atomicAdd(&s2sq[col], ss);
    }
  }
}

// ---------------- K4: BN2 affine coefficients (b2 folded in) ----------------
__global__ void k_prep2(const float* __restrict__ g, const float* __restrict__ bb,
                        const float* __restrict__ b2,
                        const float* __restrict__ s2sum, const float* __restrict__ s2sq,
                        float* __restrict__ sc2, float* __restrict__ t2, float invB)
{
  int j = threadIdx.x;   // 256
  float m = s2sum[j] * invB;
  float v = s2sq[j] * invB - m * m;
  float s = g[j] * rsqrtf(v + 1e-5f);
  sc2[j] = s;
  t2[j] = bb[j] - m * s + b2[j] * s;   // a2 = relu(s*h_raw + t2)
}

// ---------------- K5: a1 -> fc2 -> BN2+ReLU -> a2(LDS) -> fc3 -> tanh ----------------
// 64 rows/block, 1024 blocks, 4 blocks/CU (LDS ~34 KB)
__global__ __launch_bounds__(256, 4) void k_final(
    const float4* __restrict__ q, const float4* __restrict__ w1e4,
    const float* __restrict__ b1e, const _Float16* __restrict__ w2t,
    const float* __restrict__ sc2, const float* __restrict__ t2g,
    const _Float16* __restrict__ w3t, const float* __restrict__ b3,
    float* __restrict__ out)
{
  __shared__ __align__(16) float4 qs[64];                  // 1 KB
  __shared__ __align__(16) _Float16 un[64 * 260];          // 33.3 KB union
  _Float16* a1 = un;    // [64][132] during fc2 phase
  _Float16* a2 = un;    // [64][260] during fc3 phase

  int t = threadIdx.x;
  int lane = t & 63, w = t >> 6, m32 = lane & 31, hh = lane >> 5;
  size_t rowBase = (size_t)blockIdx.x * 64;

  if (t < 64) qs[t] = q[rowBase + t];
  __syncthreads();

  // ---- stage a1 ----
  {
    int j = t & 127;
    float4 w1 = w1e4[j];
    float b1v = b1e[j];
    int rb = (t >> 7) * 32;
#pragma unroll 8
    for (int i = 0; i < 32; i++) {
      float4 qv = qs[rb + i];
      float v = fmaf(w1.x, qv.x, fmaf(w1.y, qv.y, fmaf(w1.z, qv.z, fmaf(w1.w, qv.w, b1v))));
      a1[(rb + i) * 132 + j] = (_Float16)fmaxf(v, 0.f);
    }
  }
  __syncthreads();

  // ---- fc2 ----
  f32x16 acc[2][2];
#pragma unroll
  for (int mt = 0; mt < 2; mt++)
#pragma unroll
    for (int nt = 0; nt < 2; nt++)
#pragma unroll
      for (int r = 0; r < 16; r++) acc[mt][nt][r] = 0.f;

#pragma unroll
  for (int ks = 0; ks < 8; ks++) {
    int kb = ks * 16 + hh * 8;
    int kblock = ks * 2 + hh;
    f16x8 bfr[2];
#pragma unroll
    for (int nt = 0; nt < 2; nt++)
      bfr[nt] = *(const f16x8*)(w2t + (size_t)(kblock * 256 + w * 64 + nt * 32 + m32) * 8);
#pragma unroll
    for (int mt = 0; mt < 2; mt++) {
      f16x8 afr = *(const f16x8*)&a1[(mt * 32 + m32) * 132 + kb];
#pragma unroll
      for (int nt = 0; nt < 2; nt++)
        acc[mt][nt] = MFMA32(afr, bfr[nt], acc[mt][nt]);
    }
  }

  // BN2 coefficients per owned column
  float sv[2], tv[2];
#pragma unroll
  for (int nt = 0; nt < 2; nt++) {
    int col = w * 64 + nt * 32 + m32;
    sv[nt] = sc2[col];
    tv[nt] = t2g[col];
  }
  __syncthreads();   // all a1 reads done; union becomes a2

  // ---- BN2 + ReLU -> a2 (fp16, stride 260) ----
#pragma unroll
  for (int nt = 0; nt < 2; nt++) {
    int col = w * 64 + nt * 32 + m32;
#pragma unroll
    for (int mt = 0; mt < 2; mt++)
#pragma unroll
      for (int r = 0; r < 16; r++) {
        int row = mt * 32 + (r & 3) + 8 * (r >> 2) + 4 * hh;
        a2[row * 260 + col] = (_Float16)fmaxf(fmaf(acc[mt][nt][r], sv[nt], tv[nt]), 0.f);
      }
  }
  __syncthreads();

  // ---- fc3 (K = 256) ----
  f32x16 acc3[2][2];
#pragma unroll
  for (int mt = 0; mt < 2; mt++)
#pragma unroll
    for (int nt = 0; nt < 2; nt++)
#pragma unroll
      for (int r = 0; r < 16; r++) acc3[mt][nt][r] = 0.f;

#pragma unroll 4
  for (int ks = 0; ks < 16; ks++) {
    int kb = ks * 16 + hh * 8;
    int kblock = ks * 2 + hh;
    f16x8 bfr[2];
#pragma unroll
    for (int nt = 0; nt < 2; nt++)
      bfr[nt] = *(const f16x8*)(w3t + (size_t)(kblock * 256 + w * 64 + nt * 32 + m32) * 8);
#pragma unroll
    for (int mt = 0; mt < 2; mt++) {
      f16x8 afr = *(const f16x8*)&a2[(mt * 32 + m32) * 260 + kb];
#pragma unroll
      for (int nt = 0; nt < 2; nt++)
        acc3[mt][nt] = MFMA32(afr, bfr[nt], acc3[mt][nt]);
    }
  }

  // ---- tanh epilogue ----
#pragma unroll
  for (int nt = 0; nt < 2; nt++) {
    int col = w * 64 + nt * 32 + m32;
    float b3v = b3[col];
#pragma unroll
    for (int mt = 0; mt < 2; mt++)
#pragma unroll
      for (int r = 0; r < 16; r++) {
        int row = mt * 32 + (r & 3) + 8 * (r >> 2) + 4 * hh;
        out[(rowBase + row) * 256 + col] = tanh_fast(acc3[mt][nt][r] + b3v);
      }
  }
}

// ---------------- host launcher ----------------
extern "C" void kernel_launch(void* const* d_in, const int* in_sizes, int n_in,
                              void* d_out, int out_size, void* d_ws, size_t ws_size,
                              hipStream_t stream) {
  const float* x     = (const float*)d_in[0];
  const float* qp    = (const float*)d_in[1];
  const float* fc1_w = (const float*)d_in[2];
  const float* fc1_b = (const float*)d_in[3];
  const float* bn1_g = (const float*)d_in[4];
  const float* bn1_b = (const float*)d_in[5];
  const float* fc2_w = (const float*)d_in[6];
  const float* fc2_b = (const float*)d_in[7];
  const float* bn2_g = (const float*)d_in[8];
  const float* bn2_b = (const float*)d_in[9];
  const float* fc3_w = (const float*)d_in[10];
  const float* fc3_b = (const float*)d_in[11];
  float* out = (float*)d_out;
  float* ws  = (float*)d_ws;

  int B = in_sizes[0] / 4;
  int QB = B / 256;

  // ws layout (floats): q[4B] | s1[16] | s2sum[256] | s2sq[256] | w1e[512] | b1e[128]
  //                     | sc2[256] | t2[256] | w2t[16384] | w3t[32768]
  float* wq    = ws;
  float* s1    = ws + (size_t)4 * B;
  float* s2sum = s1 + 16;
  float* s2sq  = s2sum + 256;
  float* w1e   = s2sq + 256;
  float* b1e   = w1e + 512;
  float* sc2   = b1e + 128;
  float* t2    = sc2 + 256;
  _Float16* w2t = (_Float16*)(t2 + 256);
  _Float16* w3t = w2t + 32768;

  // zero accumulators: s1 + s2sum + s2sq (contiguous)
  hipMemsetAsync((void*)s1, 0, (16 + 256 + 256) * sizeof(float), stream);

  float invB = 1.0f / (float)B;

  k_quantum<<<QB + 256, 256, 0, stream>>>((const float4*)x, qp, (float4*)wq, s1, QB,
                                          fc2_w, fc3_w, w2t, w3t);
  k_prep1<<<1, 128, 0, stream>>>(fc1_w, fc1_b, bn1_g, bn1_b, s1, w1e, b1e, invB);
  k_fc2stats<<<B / 64, 256, 0, stream>>>((const float4*)wq, (const float4*)w1e, b1e,
                                         w2t, fc2_b, s2sum, s2sq);
  k_prep2<<<1, 256, 0, stream>>>(bn2_g, bn2_b, fc2_b, s2sum, s2sq, sc2, t2, invB);
  k_final<<<B / 64, 256, 0, stream>>>((const float4*)wq, (const float4*)w1e, b1e,
                                      w2t, sc2, t2, w3t, fc3_b, out);
}